// Round 9
// baseline (242.132 us; speedup 1.0000x reference)
//
#include <hip/hip_runtime.h>
#include <hip/hip_bf16.h>
#include <cstdint>

typedef __bf16 bf16x8 __attribute__((ext_vector_type(8)));
typedef __bf16 bf16x4 __attribute__((ext_vector_type(4)));
typedef short short4_ __attribute__((ext_vector_type(4)));
typedef float f32x4 __attribute__((ext_vector_type(4)));

#define SLEN 4096
#define DMODEL 1280
#define NHEADS 16
#define HD 80
#define HDP 96                   // q/k row stride (192B; conflict-free groupable)
#define VTILE_ELEMS 3328         // v tile stride (elems): [80][40] valid + pad = 6656B
#define VTILE_LDS 3584           // LDS stride per staged v tile (7 x 1KB instrs)

#define GLD_LDS16(g, l)                                                        \
  __builtin_amdgcn_global_load_lds(                                            \
      (const __attribute__((address_space(1))) void*)(g),                      \
      (__attribute__((address_space(3))) void*)(l), 16, 0, 0)

// s_waitcnt imm (gfx9 encoding): vmcnt[3:0]|expcnt[6:4]|lgkm[11:8]|vmcnt[5:4]@14
#define WAIT_VMCNT(n) __builtin_amdgcn_s_waitcnt((n & 0xF) | 0x70 | 0xF00 | ((n >> 4) << 14))

#define FENCE asm volatile("" ::: "memory")
#define BARRIER do { FENCE; __builtin_amdgcn_s_barrier(); FENCE; } while (0)

// ---------------- fused prep: cvt hidden + transpose both weights ----------------
__device__ __forceinline__ void transpose_body(const float* __restrict__ in,
                                               __bf16* __restrict__ out,
                                               int K, int N, int bx, int by, int t) {
  __shared__ float tile[32][33];
  int n0 = bx * 32, k0 = by * 32;
  int x = t & 31, y = t >> 5;  // y in 0..7
  for (int i = 0; i < 32; i += 8)
    tile[y + i][x] = in[(size_t)(k0 + y + i) * N + n0 + x];
  __syncthreads();
  for (int i = 0; i < 32; i += 8)
    out[(size_t)(n0 + y + i) * K + k0 + x] = (__bf16)tile[x][y + i];
}

__global__ __launch_bounds__(256) void prep(const float* __restrict__ hidden,
                                            __bf16* __restrict__ hid_b,
                                            const float* __restrict__ w_qkv,
                                            __bf16* __restrict__ wqkvT,
                                            const float* __restrict__ w_proj,
                                            __bf16* __restrict__ wprojT) {
  int bid = blockIdx.x, t = threadIdx.x;
  if (bid < 5120) {
    int i = bid * 256 + t;
    float4 v = ((const float4*)hidden)[i];
    bf16x4 o = { (__bf16)v.x, (__bf16)v.y, (__bf16)v.z, (__bf16)v.w };
    ((bf16x4*)hid_b)[i] = o;
  } else if (bid < 9920) {
    int b = bid - 5120;
    transpose_body(w_qkv, wqkvT, 1280, 3840, b % 120, b / 120, t);
  } else {
    int b = bid - 9920;
    transpose_body(w_proj, wprojT, 1280, 1280, b % 40, b / 40, t);
  }
}

// ===================== 4-phase 256x256 GEMM =====================
// Kept compiled for revert comparability (R8 A/B: QKV moves to gemm128 --
// 256^2 at 1 block/CU has no inter-block overlap; m114/m103 favor 128^2
// at 2 blocks/CU for this simple barrier-phased schedule).
template <int I0, int J0>
__device__ __forceinline__ void mfma16(f32x4 (&acc)[8][4], bf16x8 (&af)[4][2],
                                       bf16x8 (&bfr)[4][2]) {
  __builtin_amdgcn_s_setprio(1);
#pragma unroll
  for (int kk = 0; kk < 2; ++kk)
#pragma unroll
    for (int i = 0; i < 4; ++i)
#pragma unroll
      for (int j = 0; j < 2; ++j)
        acc[I0 + i][J0 + j] = __builtin_amdgcn_mfma_f32_16x16x32_bf16(
            bfr[J0 + j][kk], af[i][kk], acc[I0 + i][J0 + j], 0, 0, 0);
  __builtin_amdgcn_s_setprio(0);
}

__global__ __launch_bounds__(512, 2) void gemm256(const __bf16* __restrict__ A,
                                                  const __bf16* __restrict__ Bt,
                                                  const float* __restrict__ bias,
                                                  __bf16* __restrict__ C,
                                                  int M, int N, int K) {
  __shared__ __attribute__((aligned(1024))) __bf16 As[2][256 * 64];
  __shared__ __attribute__((aligned(1024))) __bf16 Bs[2][256 * 64];

  const int t = threadIdx.x;
  const int lane = t & 63, wave = t >> 6;
  const int quad = lane >> 4, l15 = lane & 15;
  const int wm = wave >> 2, wn = wave & 3;

  const int mb = M >> 8;
  const int cpx = gridDim.x >> 3;
  const int wg = (blockIdx.x & 7) * cpx + (blockIdx.x >> 3);
  const int bm = (wg % mb) * 256, bn = (wg / mb) * 256;

  const __bf16* Ab = A + (size_t)bm * K;
  const __bf16* Bb = Bt + (size_t)bn * K;

  auto stage = [&](const __bf16* g, __bf16* l, int row0, int kt) {
    GLD_LDS16(g + (size_t)(row0 + (lane >> 3)) * K + kt * 64 +
                  (((lane & 7) ^ ((lane >> 3) & 7)) << 3),
              l + row0 * 64);
  };
  auto lda = [&](bf16x8 (&dst)[4][2], const __bf16* Al, int I0) {
#pragma unroll
    for (int i = 0; i < 4; ++i)
#pragma unroll
      for (int kk = 0; kk < 2; ++kk) {
        int row = wm * 128 + (I0 + i) * 16 + l15;
        int c = (kk * 64 + quad * 16) ^ ((l15 & 7) << 4);
        dst[i][kk] = *(const bf16x8*)&Al[row * 64 + (c >> 1)];
      }
  };
  auto ldb = [&](bf16x8 (&dst)[2][2], const __bf16* Bl, int J0) {
#pragma unroll
    for (int j = 0; j < 2; ++j)
#pragma unroll
      for (int kk = 0; kk < 2; ++kk) {
        int row = wn * 64 + (J0 + j) * 16 + l15;
        int c = (kk * 64 + quad * 16) ^ ((l15 & 7) << 4);
        dst[j][kk] = *(const bf16x8*)&Bl[row * 64 + (c >> 1)];
      }
  };

  const int aw = wave * 8;
  const int be0 = (wave >> 2) * 64 + (wave & 3) * 8;
  const int niter = K >> 6;

  stage(Ab, As[0], aw, 0);        stage(Ab, As[0], 128 + aw, 0);
  stage(Bb, Bs[0], be0, 0);       stage(Bb, Bs[0], be0 + 128, 0);
  stage(Ab, As[0], 64 + aw, 0);   stage(Ab, As[0], 192 + aw, 0);
  stage(Bb, Bs[0], be0 + 32, 0);  stage(Bb, Bs[0], be0 + 160, 0);
  stage(Ab, As[1], aw, 1);        stage(Ab, As[1], 128 + aw, 1);
  stage(Bb, Bs[1], be0, 1);       stage(Bb, Bs[1], be0 + 128, 1);
  WAIT_VMCNT(4);
  BARRIER;

  f32x4 acc[8][4] = {};
  bf16x8 af[4][2], bfr[4][2];

  for (int it = 0; it < niter; ++it) {
    const int cur = it & 1;
    const __bf16* Ac = As[cur];
    const __bf16* Bc = Bs[cur];
    __bf16* An = As[cur ^ 1];
    __bf16* Bn = Bs[cur ^ 1];
    const bool p1 = it + 1 < niter, p2 = it + 2 < niter;

    lda(af, Ac, 0);
    ldb(reinterpret_cast<bf16x8(&)[2][2]>(bfr[0]), Bc, 0);
    if (p1) { stage(Ab, An, 64 + aw, it + 1); stage(Ab, An, 192 + aw, it + 1); }
    BARRIER;
    mfma16<0, 0>(acc, af, bfr);
    BARRIER;

    ldb(reinterpret_cast<bf16x8(&)[2][2]>(bfr[2]), Bc, 2);
    if (p1) { stage(Bb, Bn, be0 + 32, it + 1); stage(Bb, Bn, be0 + 160, it + 1); }
    BARRIER;
    mfma16<0, 2>(acc, af, bfr);
    BARRIER;

    lda(af, Ac, 4);
    if (p2) { stage(Ab, (__bf16*)Ac, aw, it + 2); stage(Ab, (__bf16*)Ac, 128 + aw, it + 2); }
    BARRIER;
    mfma16<4, 0>(acc, af, bfr);
    BARRIER;

    if (p2) { stage(Bb, (__bf16*)Bc, be0, it + 2); stage(Bb, (__bf16*)Bc, be0 + 128, it + 2); }
    BARRIER;
    mfma16<4, 2>(acc, af, bfr);
    if (p2) { WAIT_VMCNT(4); }
    else    { WAIT_VMCNT(0); }
    BARRIER;
  }

  float4 bv[4];
#pragma unroll
  for (int j = 0; j < 4; ++j)
    bv[j] = *(const float4*)&bias[bn + wn * 64 + j * 16 + quad * 4];
#pragma unroll
  for (int i = 0; i < 8; ++i) {
    size_t row = (size_t)(bm + wm * 128 + i * 16 + l15);
#pragma unroll
    for (int j = 0; j < 4; ++j) {
      int col = bn + wn * 64 + j * 16 + quad * 4;
      const float* bp = (const float*)&bv[j];
      bf16x4 ov;
#pragma unroll
      for (int r = 0; r < 4; ++r) ov[r] = (__bf16)(acc[i][j][r] + bp[r]);
      *(bf16x4*)&C[row * N + col] = ov;
    }
  }
}

// ===================== 4-phase 128x128 GEMM =====================
// Proven on proj since R5; now also runs QKV (R8 A/B): 64 KiB LDS ->
// 2 blocks/CU -> m114 inter-block overlap. store_bf16 flag = epilogue-only.
template <int I0, int J0>
__device__ __forceinline__ void mfma8(f32x4 (&acc)[4][4], bf16x8 (&af)[2][2],
                                      bf16x8 (&bfr)[4][2]) {
  __builtin_amdgcn_s_setprio(1);
#pragma unroll
  for (int kk = 0; kk < 2; ++kk)
#pragma unroll
    for (int i = 0; i < 2; ++i)
#pragma unroll
      for (int j = 0; j < 2; ++j)
        acc[I0 + i][J0 + j] = __builtin_amdgcn_mfma_f32_16x16x32_bf16(
            bfr[J0 + j][kk], af[i][kk], acc[I0 + i][J0 + j], 0, 0, 0);
  __builtin_amdgcn_s_setprio(0);
}

__global__ __launch_bounds__(256, 2) void gemm128(const __bf16* __restrict__ A,
                                                  const __bf16* __restrict__ Bt,
                                                  const float* __restrict__ bias,
                                                  void* __restrict__ C,
                                                  int M, int N, int K, int store_bf16) {
  __shared__ __attribute__((aligned(1024))) __bf16 As[2][128 * 64];
  __shared__ __attribute__((aligned(1024))) __bf16 Bs[2][128 * 64];

  const int t = threadIdx.x;
  const int lane = t & 63, wave = t >> 6;
  const int quad = lane >> 4, l15 = lane & 15;
  const int wm = wave >> 1, wn = wave & 1;

  // XCD-bijective block swizzle (grids 960 and 320, both % 8 == 0)
  const int mb = M >> 7;
  const int cpx = gridDim.x >> 3;
  const int wg = (blockIdx.x & 7) * cpx + (blockIdx.x >> 3);
  const int bm = (wg % mb) * 128, bn = (wg / mb) * 128;

  const __bf16* Ab = A + (size_t)bm * K;
  const __bf16* Bb = Bt + (size_t)bn * K;

  auto stage = [&](const __bf16* g, __bf16* l, int row0, int kt) {
    GLD_LDS16(g + (size_t)(row0 + (lane >> 3)) * K + kt * 64 +
                  (((lane & 7) ^ ((lane >> 3) & 7)) << 3),
              l + row0 * 64);
  };
  auto lda2 = [&](bf16x8 (&dst)[2][2], const __bf16* Al, int I0) {
#pragma unroll
    for (int i = 0; i < 2; ++i)
#pragma unroll
      for (int kk = 0; kk < 2; ++kk) {
        int row = wm * 64 + (I0 + i) * 16 + l15;
        int c = (kk * 64 + quad * 16) ^ ((l15 & 7) << 4);
        dst[i][kk] = *(const bf16x8*)&Al[row * 64 + (c >> 1)];
      }
  };
  auto ldb2 = [&](bf16x8 (&dst)[2][2], const __bf16* Bl, int J0) {
#pragma unroll
    for (int j = 0; j < 2; ++j)
#pragma unroll
      for (int kk = 0; kk < 2; ++kk) {
        int row = wn * 64 + (J0 + j) * 16 + l15;
        int c = (kk * 64 + quad * 16) ^ ((l15 & 7) << 4);
        dst[j][kk] = *(const bf16x8*)&Bl[row * 64 + (c >> 1)];
      }
  };

  const int aw = wave * 8;   // wave's 8-row slice within a 32-row quarter
  const int niter = K >> 6;

  // Region map (rows): Ae/Be = {0..31, 64..95}; Ao/Bo = {32..63, 96..127}.
  stage(Ab, As[0], aw, 0);        stage(Ab, As[0], 64 + aw, 0);   // t0.Ae
  stage(Bb, Bs[0], aw, 0);        stage(Bb, Bs[0], 64 + aw, 0);   // t0.Be
  stage(Ab, As[0], 32 + aw, 0);   stage(Ab, As[0], 96 + aw, 0);   // t0.Ao
  stage(Bb, Bs[0], 32 + aw, 0);   stage(Bb, Bs[0], 96 + aw, 0);   // t0.Bo
  stage(Ab, As[1], aw, 1);        stage(Ab, As[1], 64 + aw, 1);   // t1.Ae
  stage(Bb, Bs[1], aw, 1);        stage(Bb, Bs[1], 64 + aw, 1);   // t1.Be
  WAIT_VMCNT(4);
  BARRIER;

  f32x4 acc[4][4] = {};
  bf16x8 af[2][2], bfr[4][2];

  for (int it = 0; it < niter; ++it) {
    const int cur = it & 1;
    const __bf16* Ac = As[cur];
    const __bf16* Bc = Bs[cur];
    __bf16* An = As[cur ^ 1];
    __bf16* Bn = Bs[cur ^ 1];
    const bool p1 = it + 1 < niter, p2 = it + 2 < niter;

    // ph1: read A(i0-1)+B(j0-1) [Ae/Be]; stage (t+1).Ao
    lda2(af, Ac, 0);
    ldb2(reinterpret_cast<bf16x8(&)[2][2]>(bfr[0]), Bc, 0);
    if (p1) { stage(Ab, An, 32 + aw, it + 1); stage(Ab, An, 96 + aw, it + 1); }
    BARRIER;
    mfma8<0, 0>(acc, af, bfr);
    BARRIER;

    // ph2: read B(j2-3) [Bo]; stage (t+1).Bo
    ldb2(reinterpret_cast<bf16x8(&)[2][2]>(bfr[2]), Bc, 2);
    if (p1) { stage(Bb, Bn, 32 + aw, it + 1); stage(Bb, Bn, 96 + aw, it + 1); }
    BARRIER;
    mfma8<0, 2>(acc, af, bfr);
    BARRIER;

    // ph3: read A(i2-3) [Ao]; stage (t+2).Ae into cur (dead since ph1)
    lda2(af, Ac, 2);
    if (p2) { stage(Ab, (__bf16*)Ac, aw, it + 2); stage(Ab, (__bf16*)Ac, 64 + aw, it + 2); }
    BARRIER;
    mfma8<2, 0>(acc, af, bfr);
    BARRIER;

    // ph4: pure-reg MFMA; stage (t+2).Be into cur (dead since ph1); counted vmcnt
    if (p2) { stage(Bb, (__bf16*)Bc, aw, it + 2); stage(Bb, (__bf16*)Bc, 64 + aw, it + 2); }
    BARRIER;
    mfma8<2, 2>(acc, af, bfr);
    if (p2) { WAIT_VMCNT(4); }   // drains t+1.Ao/Bo; leaves t+2.Ae/Be in flight
    else    { WAIT_VMCNT(0); }   // tail: full drain
    BARRIER;
  }

  float4 bv4[4];
#pragma unroll
  for (int j = 0; j < 4; ++j)
    bv4[j] = *(const float4*)&bias[bn + wn * 64 + j * 16 + quad * 4];
#pragma unroll
  for (int i = 0; i < 4; ++i) {
    size_t row = (size_t)(bm + wm * 64 + i * 16 + l15);
#pragma unroll
    for (int j = 0; j < 4; ++j) {
      int col = bn + wn * 64 + j * 16 + quad * 4;
      const float* bp = (const float*)&bv4[j];
      if (store_bf16) {
        bf16x4 ov;
#pragma unroll
        for (int r = 0; r < 4; ++r) ov[r] = (__bf16)(acc[i][j][r] + bp[r]);
        *(bf16x4*)&((__bf16*)C)[row * N + col] = ov;
      } else {
        float4 fv;
        fv.x = acc[i][j][0] + bp[0];
        fv.y = acc[i][j][1] + bp[1];
        fv.z = acc[i][j][2] + bp[2];
        fv.w = acc[i][j][3] + bp[3];
        *(float4*)&((float*)C)[row * N + col] = fv;
      }
    }
  }
}

// --- RoPE q,k + pack (vectorized b128 loads/stores; on-device trig):
//   qp, kp: (H, S, 96), d 80..95 zero; q pre-scaled by log2e/sqrt(80)
//   vt: per-head, per-32-key tiles [80 d][40 pos], KEY-PERMUTED
//   (permutation == x32 MFMA operand k->key map; PV consumes vv directly)
__global__ __launch_bounds__(256) void rope_pack(const __bf16* __restrict__ qkv,
                                                 const float* __restrict__ freqs,
                                                 __bf16* __restrict__ qp,
                                                 __bf16* __restrict__ kp,
                                                 __bf16* __restrict__ vt) {
  const float QSCALE = 0.11180339887498949f * 1.44269504088896340f;
  int h = blockIdx.y;
  int s0 = blockIdx.x * 64;
  int t = threadIdx.x;
  int sp = t >> 2, l4 = t & 3;
  int s = s0 + sp;
  const __bf16* row = qkv + (size_t)s * 3840 + h * 80;
  __bf16* qo = qp + (size_t)(h * SLEN + s) * HDP;
  __bf16* ko = kp + (size_t)(h * SLEN + s) * HDP;

  __shared__ float vtile[64][81];

  for (int c = l4; c < 10; c += 4) {
    int base = (c < 5) ? c * 8 : (c - 5) * 8;
    bf16x8 xa = *(const bf16x8*)(row + base);
    bf16x8 xb = *(const bf16x8*)(row + base + 40);
    bf16x8 ya = *(const bf16x8*)(row + 1280 + base);
    bf16x8 yb = *(const bf16x8*)(row + 1280 + base + 40);
    float4 f0 = *(const float4*)(freqs + s * 40 + base);
    float4 f1 = *(const float4*)(freqs + s * 40 + base + 4);
    float fr[8] = {f0.x, f0.y, f0.z, f0.w, f1.x, f1.y, f1.z, f1.w};
    bf16x8 qv, kv;
#pragma unroll
    for (int e = 0; e < 8; ++e) {
      float cs = __builtin_cosf(fr[e]), sn = __builtin_sinf(fr[e]);
      float x1 = (float)xa[e], x2 = (float)xb[e];
      float y1 = (float)ya[e], y2 = (float)yb[e];
      float qvv, kvv;
      if (c < 5) { qvv = x1 * cs - x2 * sn; kvv = y1 * cs - y2 * sn; }
      else       { qvv = x1 * sn + x2 * cs; kvv = y1 * sn + y2 * cs; }
      qv[e] = (__bf16)(qvv * QSCALE);
      kv[e] = (__bf16)kvv;
    }
    *(bf16x8*)(qo + c * 8) = qv;
    *(bf16x8*)(ko + c * 8) = kv;
  }
  {
    bf16x8 z = {};
    if (l4 == 0) *(bf16x8*)(qo + 80) = z;
    if (l4 == 1) *(bf16x8*)(qo + 88) = z;
    if (l4 == 2) *(bf16x8*)(ko + 80) = z;
    if (l4 == 3) *(bf16x8*)(ko + 88) = z;
  }

  for (int c = l4; c < 10; c += 4) {
    bf16x8 v = *(const bf16x8*)(row + 2560 + c * 8);
#pragma unroll
    for (int e = 0; e < 8; ++e)
      vtile[sp][c * 8 + e] = (float)v[e];
  }
  __syncthreads();

  for (int idx = t; idx < 640; idx += 256) {
    int c2 = idx >= 320;
    int rem = idx - (c2 ? 320 : 0);
    int d = rem >> 2, kc = rem & 3;
    __bf16* tb = vt + (size_t)(h * (SLEN / 32) + (s0 >> 5) + c2) * VTILE_ELEMS;
    bf16x8 ov;
#pragma unroll
    for (int r = 0; r < 4; ++r) {
      ov[r]     = (__bf16)vtile[c2 * 32 + kc * 4 + r][d];
      ov[r + 4] = (__bf16)vtile[c2 * 32 + 16 + kc * 4 + r][d];
    }
    *(bf16x8*)(tb + d * 40 + kc * 8) = ov;
  }
}

// ----------------- flash attention: 32 q-rows/wave, b128 V reads -----------------
// PV x32 MFMA (R3); T5 setprio (R4); XCD-locality remap (R8, kept: -1.6us).
__global__ __launch_bounds__(256) void flash_attn(const __bf16* __restrict__ qp,
                                                  const __bf16* __restrict__ kp,
                                                  const __bf16* __restrict__ vt,
                                                  const int* __restrict__ cu, int nseg,
                                                  __bf16* __restrict__ out) {
  const float MEXP = 16.0f;
  int bid = blockIdx.x;
  int p = bid & 63;            // (head, quarter) pair
  int qs8 = bid >> 6;          // q sub-tile 0..7
  int h = p >> 2;
  int q0 = (p & 3) * (SLEN / 4) + qs8 * 128;
  int seg = 0;
  for (int i = 1; i < nseg; ++i)
    if (cu[i] <= q0) seg = i;
  int kstart = cu[seg], kend = cu[seg + 1];

  int t = threadIdx.x;
  int lane = t & 63, wave = t >> 6;
  int quad = lane >> 4, l15 = lane & 15;

  __shared__ __attribute__((aligned(16))) __bf16 Ks[2][64 * HDP];       // 2x12288 B
  __shared__ __attribute__((aligned(16))) __bf16 Vs[2][2 * VTILE_LDS];  // 2x14336 B

  bf16x8 qf[2][3];
#pragma unroll
  for (int qs = 0; qs < 2; ++qs) {
    const __bf16* qptr = qp + (size_t)(h * SLEN + q0 + wave * 32 + qs * 16 + l15) * HDP + quad * 8;
    qf[qs][0] = *(const bf16x8*)(qptr);
    qf[qs][1] = *(const bf16x8*)(qptr + 32);
    qf[qs][2] = *(const bf16x8*)(qptr + 64);
  }

  f32x4 o[2][5] = {};
  float l_p[2] = {0.f, 0.f};

  const __bf16* gK = kp + (size_t)(h * SLEN + kstart) * HDP + lane * 8;
  const __bf16* gV = vt + (size_t)(h * (SLEN / 32) + (kstart >> 5)) * VTILE_ELEMS + lane * 8;

  const int niter = (kend - kstart) >> 6;

  auto stage = [&](int kn, int buf) {
    const __bf16* ksrc = gK + (size_t)kn * (64 * HDP);
    const __bf16* vsrc = gV + (size_t)kn * (2 * VTILE_ELEMS);
#pragma unroll
    for (int i0 = 0; i0 < 7; ++i0) {
      int i = wave * 7 + i0;
      int ii = i < 26 ? i : 25;   // dummies re-issue slot 25 (idempotent)
      if (ii < 12)
        GLD_LDS16(ksrc + ii * 512, &Ks[buf][ii * 512]);
      else if (ii < 19)
        GLD_LDS16(vsrc + (ii - 12) * 512, &Vs[buf][(ii - 12) * 512]);
      else
        GLD_LDS16(vsrc + VTILE_ELEMS + (ii - 19) * 512, &Vs[buf][VTILE_LDS + (ii - 19) * 512]);
    }
  };

  stage(0, 0);

  for (int it = 0; it < niter; ++it) {
    const int cur = it & 1, nxt = cur ^ 1;
    const int kn = (it + 1 < niter) ? it + 1 : niter - 1;
    stage(kn, nxt);
    asm volatile("" ::: "memory");
    WAIT_VMCNT(7);
    __builtin_amdgcn_s_barrier();
    asm volatile("" ::: "memory");

    f32x4 sc[2][4];
    __builtin_amdgcn_s_setprio(1);
#pragma unroll
    for (int nt = 0; nt < 4; ++nt) {
      sc[0][nt] = f32x4{-MEXP, -MEXP, -MEXP, -MEXP};
      sc[1][nt] = sc[0][nt];
#pragma unroll
      for (int c = 0; c < 3; ++c) {
        bf16x8 kf = *(const bf16x8*)&Ks[cur][(nt * 16 + l15) * HDP + quad * 8 + c * 32];
        sc[0][nt] = __builtin_amdgcn_mfma_f32_16x16x32_bf16(kf, qf[0][c], sc[0][nt], 0, 0, 0);
        sc[1][nt] = __builtin_amdgcn_mfma_f32_16x16x32_bf16(kf, qf[1][c], sc[1][nt], 0, 0, 0);
      }
    }
    __builtin_amdgcn_s_setprio(0);

    bf16x4 pf[2][4];
#pragma unroll
    for (int qs = 0; qs < 2; ++qs)
#pragma unroll
      for (int nt = 0; nt < 4; ++nt)
#pragma unroll
        for (int r = 0; r < 4; ++r) {
          float pexp = __builtin_amdgcn_exp2f(sc[qs][nt][r]);
          l_p[qs] += pexp;
          pf[qs][nt][r] = (__bf16)pexp;
        }

    __builtin_amdgcn_s_setprio(1);
#pragma unroll
    for (int g = 0; g < 2; ++g) {
      bf16x8 pc[2];
#pragma unroll
      for (int qs = 0; qs < 2; ++qs)
        pc[qs] = __builtin_shufflevector(pf[qs][g * 2], pf[qs][g * 2 + 1],
                                         0, 1, 2, 3, 4, 5, 6, 7);
#pragma unroll
      for (int dt = 0; dt < 5; ++dt) {
        bf16x8 vv = *(const bf16x8*)&Vs[cur][g * VTILE_LDS + (dt * 16 + l15) * 40 + quad * 8];
#pragma unroll
        for (int qs = 0; qs < 2; ++qs)
          o[qs][dt] = __builtin_amdgcn_mfma_f32_16x16x32_bf16(vv, pc[qs], o[qs][dt], 0, 0, 0);
      }
    }
    __builtin_amdgcn_s_setprio(0);

    asm volatile("" ::: "memory");
    __builtin_amdgcn_s_barrier();
    asm volatile("" ::: "memory");
  }

#pragma unroll
  for (int qs = 0; qs < 2; ++qs) {
    float l = l_p[qs];
    l += __shfl_xor(l, 16);
    l += __shfl_xor(l, 32);
    float rinv = 1.0f / l;
    int qrow = q0 + wave * 32 + qs * 16 + l15;
#pragma unroll
    for (int dt = 0; dt < 5; ++dt) {
      bf16x4 ov;
#pragma unroll
      for (int r = 0; r < 4; ++r)
        ov[r] = (__bf16)(o[qs][dt][r] * rinv);
      *(bf16x4*)&out[(size_t)qrow * DMODEL + h * 80 + dt * 16 + quad * 4] = ov;
    }
  }
}

extern "C" void kernel_launch(void* const* d_in, const int* in_sizes, int n_in,
                              void* d_out, int out_size, void* d_ws, size_t ws_size,
                              hipStream_t stream) {
  const float* hidden = (const float*)d_in[0];
  const int* cu       = (const int*)d_in[1];
  const float* freqs  = (const float*)d_in[2];
  const float* w_qkv  = (const float*)d_in[3];
  const float* b_qkv  = (const float*)d_in[4];
  const float* w_proj = (const float*)d_in[5];
  const float* b_proj = (const float*)d_in[6];
  float* out = (float*)d_out;

  char* ws = (char*)d_ws;
  size_t off = 0;
  auto alloc = [&](size_t bytes) {
    char* p = ws + off;
    off += (bytes + 255) & ~(size_t)255;
    return p;
  };
  __bf16* hid_b  = (__bf16*)alloc((size_t)SLEN * DMODEL * 2);
  __bf16* wqkvT  = (__bf16*)alloc((size_t)3840 * 1280 * 2);
  __bf16* wprojT = (__bf16*)alloc((size_t)1280 * 1280 * 2);
  __bf16* qkvb   = (__bf16*)alloc((size_t)SLEN * 3840 * 2);
  __bf16* qp     = (__bf16*)alloc((size_t)NHEADS * SLEN * HDP * 2);
  __bf16* kp     = (__bf16*)alloc((size_t)NHEADS * SLEN * HDP * 2 + 1024);
  __bf16* vt     = (__bf16*)alloc((size_t)NHEADS * (SLEN / 32) * VTILE_ELEMS * 2 + 1024);
  __bf16* attn   = hid_b;  // alias: hid_b dead after qkv GEMM

  prep<<<11520, 256, 0, stream>>>(hidden, hid_b, w_qkv, wqkvT, w_proj, wprojT);
  // R8 A/B: QKV GEMM on the 128^2 / 2-blocks-per-CU kernel (was gemm256)
  gemm128<<<dim3((SLEN / 128) * (3840 / 128)), 256, 0, stream>>>(hid_b, wqkvT, b_qkv, qkvb,
                                                                 SLEN, 3840, 1280, 1);
  rope_pack<<<dim3(SLEN / 64, NHEADS), 256, 0, stream>>>(qkvb, freqs, qp, kp, vt);
  int nseg = in_sizes[1] - 1;
  flash_attn<<<dim3((SLEN / 128) * NHEADS), 256, 0, stream>>>(qp, kp, vt, cu, nseg, attn);
  gemm128<<<dim3((SLEN / 128) * (DMODEL / 128)), 256, 0, stream>>>(attn, wprojT, b_proj, out,
                                                                   SLEN, DMODEL, 1280, 0);
}

// Round 10
// 226.387 us; speedup vs baseline: 1.0695x; 1.0695x over previous
//
#include <hip/hip_runtime.h>
#include <hip/hip_bf16.h>
#include <cstdint>

typedef __bf16 bf16x8 __attribute__((ext_vector_type(8)));
typedef __bf16 bf16x4 __attribute__((ext_vector_type(4)));
typedef short short4_ __attribute__((ext_vector_type(4)));
typedef float f32x4 __attribute__((ext_vector_type(4)));

#define SLEN 4096
#define DMODEL 1280
#define NHEADS 16
#define HD 80
#define HDP 96                   // q/k row stride (192B; conflict-free groupable)
#define VTILE_ELEMS 3328         // v tile stride (elems): [80][40] valid + pad = 6656B
#define VTILE_LDS 3584           // LDS stride per staged v tile (7 x 1KB instrs)

#define GLD_LDS16(g, l)                                                        \
  __builtin_amdgcn_global_load_lds(                                            \
      (const __attribute__((address_space(1))) void*)(g),                      \
      (__attribute__((address_space(3))) void*)(l), 16, 0, 0)

// s_waitcnt imm (gfx9 encoding): vmcnt[3:0]|expcnt[6:4]|lgkm[11:8]|vmcnt[5:4]@14
#define WAIT_VMCNT(n) __builtin_amdgcn_s_waitcnt((n & 0xF) | 0x70 | 0xF00 | ((n >> 4) << 14))

#define FENCE asm volatile("" ::: "memory")
#define BARRIER do { FENCE; __builtin_amdgcn_s_barrier(); FENCE; } while (0)

// ---------------- fused prep: cvt hidden + transpose both weights ----------------
__device__ __forceinline__ void transpose_body(const float* __restrict__ in,
                                               __bf16* __restrict__ out,
                                               int K, int N, int bx, int by, int t) {
  __shared__ float tile[32][33];
  int n0 = bx * 32, k0 = by * 32;
  int x = t & 31, y = t >> 5;  // y in 0..7
  for (int i = 0; i < 32; i += 8)
    tile[y + i][x] = in[(size_t)(k0 + y + i) * N + n0 + x];
  __syncthreads();
  for (int i = 0; i < 32; i += 8)
    out[(size_t)(n0 + y + i) * K + k0 + x] = (__bf16)tile[x][y + i];
}

__global__ __launch_bounds__(256) void prep(const float* __restrict__ hidden,
                                            __bf16* __restrict__ hid_b,
                                            const float* __restrict__ w_qkv,
                                            __bf16* __restrict__ wqkvT,
                                            const float* __restrict__ w_proj,
                                            __bf16* __restrict__ wprojT) {
  int bid = blockIdx.x, t = threadIdx.x;
  if (bid < 5120) {
    int i = bid * 256 + t;
    float4 v = ((const float4*)hidden)[i];
    bf16x4 o = { (__bf16)v.x, (__bf16)v.y, (__bf16)v.z, (__bf16)v.w };
    ((bf16x4*)hid_b)[i] = o;
  } else if (bid < 9920) {
    int b = bid - 5120;
    transpose_body(w_qkv, wqkvT, 1280, 3840, b % 120, b / 120, t);
  } else {
    int b = bid - 9920;
    transpose_body(w_proj, wprojT, 1280, 1280, b % 40, b / 40, t);
  }
}

// ===================== 4-phase 256x256 GEMM (QKV path) =====================
// Measured-best (51.3us, MfmaUtil 29%, conflicts=0) -- FROZEN. R8's A/B
// (QKV on 128^2 / 2-blocks-per-CU) measured 70.5us / MfmaUtil 22%: smaller
// per-wave MFMA clusters double relative barrier overhead; REFUTED, reverted.
template <int I0, int J0>
__device__ __forceinline__ void mfma16(f32x4 (&acc)[8][4], bf16x8 (&af)[4][2],
                                       bf16x8 (&bfr)[4][2]) {
  __builtin_amdgcn_s_setprio(1);
#pragma unroll
  for (int kk = 0; kk < 2; ++kk)
#pragma unroll
    for (int i = 0; i < 4; ++i)
#pragma unroll
      for (int j = 0; j < 2; ++j)
        acc[I0 + i][J0 + j] = __builtin_amdgcn_mfma_f32_16x16x32_bf16(
            bfr[J0 + j][kk], af[i][kk], acc[I0 + i][J0 + j], 0, 0, 0);
  __builtin_amdgcn_s_setprio(0);
}

__global__ __launch_bounds__(512, 2) void gemm256(const __bf16* __restrict__ A,
                                                  const __bf16* __restrict__ Bt,
                                                  const float* __restrict__ bias,
                                                  __bf16* __restrict__ C,
                                                  int M, int N, int K) {
  __shared__ __attribute__((aligned(1024))) __bf16 As[2][256 * 64];
  __shared__ __attribute__((aligned(1024))) __bf16 Bs[2][256 * 64];

  const int t = threadIdx.x;
  const int lane = t & 63, wave = t >> 6;
  const int quad = lane >> 4, l15 = lane & 15;
  const int wm = wave >> 2, wn = wave & 3;

  // XCD-bijective block swizzle (grid is a multiple of 8)
  const int mb = M >> 8;
  const int cpx = gridDim.x >> 3;
  const int wg = (blockIdx.x & 7) * cpx + (blockIdx.x >> 3);
  const int bm = (wg % mb) * 256, bn = (wg / mb) * 256;

  const __bf16* Ab = A + (size_t)bm * K;
  const __bf16* Bb = Bt + (size_t)bn * K;

  auto stage = [&](const __bf16* g, __bf16* l, int row0, int kt) {
    GLD_LDS16(g + (size_t)(row0 + (lane >> 3)) * K + kt * 64 +
                  (((lane & 7) ^ ((lane >> 3) & 7)) << 3),
              l + row0 * 64);
  };
  auto lda = [&](bf16x8 (&dst)[4][2], const __bf16* Al, int I0) {
#pragma unroll
    for (int i = 0; i < 4; ++i)
#pragma unroll
      for (int kk = 0; kk < 2; ++kk) {
        int row = wm * 128 + (I0 + i) * 16 + l15;
        int c = (kk * 64 + quad * 16) ^ ((l15 & 7) << 4);
        dst[i][kk] = *(const bf16x8*)&Al[row * 64 + (c >> 1)];
      }
  };
  auto ldb = [&](bf16x8 (&dst)[2][2], const __bf16* Bl, int J0) {
#pragma unroll
    for (int j = 0; j < 2; ++j)
#pragma unroll
      for (int kk = 0; kk < 2; ++kk) {
        int row = wn * 64 + (J0 + j) * 16 + l15;
        int c = (kk * 64 + quad * 16) ^ ((l15 & 7) << 4);
        dst[j][kk] = *(const bf16x8*)&Bl[row * 64 + (c >> 1)];
      }
  };

  const int aw = wave * 8;                              // A line wave base
  const int be0 = (wave >> 2) * 64 + (wave & 3) * 8;    // B stripe wave base
  const int niter = K >> 6;

  // ---- prologue: tile0 complete + tile1 A-even/B-even (12 lines) ----
  stage(Ab, As[0], aw, 0);        stage(Ab, As[0], 128 + aw, 0);   // t0.Ae
  stage(Bb, Bs[0], be0, 0);       stage(Bb, Bs[0], be0 + 128, 0);  // t0.Be
  stage(Ab, As[0], 64 + aw, 0);   stage(Ab, As[0], 192 + aw, 0);   // t0.Ao
  stage(Bb, Bs[0], be0 + 32, 0);  stage(Bb, Bs[0], be0 + 160, 0);  // t0.Bo
  stage(Ab, As[1], aw, 1);        stage(Ab, As[1], 128 + aw, 1);   // t1.Ae
  stage(Bb, Bs[1], be0, 1);       stage(Bb, Bs[1], be0 + 128, 1);  // t1.Be
  WAIT_VMCNT(4);                  // drain through t0.Bo -> tile0 resident
  BARRIER;

  f32x4 acc[8][4] = {};
  bf16x8 af[4][2], bfr[4][2];

  for (int it = 0; it < niter; ++it) {
    const int cur = it & 1;
    const __bf16* Ac = As[cur];
    const __bf16* Bc = Bs[cur];
    __bf16* An = As[cur ^ 1];
    __bf16* Bn = Bs[cur ^ 1];
    const bool p1 = it + 1 < niter, p2 = it + 2 < niter;

    // ph1: read A(i0-3)+B(j0-1); stage (t+1).A-odd
    lda(af, Ac, 0);
    ldb(reinterpret_cast<bf16x8(&)[2][2]>(bfr[0]), Bc, 0);
    if (p1) { stage(Ab, An, 64 + aw, it + 1); stage(Ab, An, 192 + aw, it + 1); }
    BARRIER;
    mfma16<0, 0>(acc, af, bfr);
    BARRIER;

    // ph2: read B(j2-3); stage (t+1).B-odd
    ldb(reinterpret_cast<bf16x8(&)[2][2]>(bfr[2]), Bc, 2);
    if (p1) { stage(Bb, Bn, be0 + 32, it + 1); stage(Bb, Bn, be0 + 160, it + 1); }
    BARRIER;
    mfma16<0, 2>(acc, af, bfr);
    BARRIER;

    // ph3: read A(i4-7); stage (t+2).A-even into cur buf (dead since ph1)
    lda(af, Ac, 4);
    if (p2) { stage(Ab, (__bf16*)Ac, aw, it + 2); stage(Ab, (__bf16*)Ac, 128 + aw, it + 2); }
    BARRIER;
    mfma16<4, 0>(acc, af, bfr);
    BARRIER;

    // ph4: pure-reg MFMA; stage (t+2).B-even (dead since ph1); counted vmcnt
    if (p2) { stage(Bb, (__bf16*)Bc, be0, it + 2); stage(Bb, (__bf16*)Bc, be0 + 128, it + 2); }
    BARRIER;
    mfma16<4, 2>(acc, af, bfr);
    if (p2) { WAIT_VMCNT(4); }   // drains t+1.Ao/Bo; leaves t+2.Ae/Be in flight
    else    { WAIT_VMCNT(0); }   // tail: full drain
    BARRIER;
  }

  float4 bv[4];
#pragma unroll
  for (int j = 0; j < 4; ++j)
    bv[j] = *(const float4*)&bias[bn + wn * 64 + j * 16 + quad * 4];
#pragma unroll
  for (int i = 0; i < 8; ++i) {
    size_t row = (size_t)(bm + wm * 128 + i * 16 + l15);
#pragma unroll
    for (int j = 0; j < 4; ++j) {
      int col = bn + wn * 64 + j * 16 + quad * 4;
      const float* bp = (const float*)&bv[j];
      bf16x4 ov;
#pragma unroll
      for (int r = 0; r < 4; ++r) ov[r] = (__bf16)(acc[i][j][r] + bp[r]);
      *(bf16x4*)&C[row * N + col] = ov;
    }
  }
}

// ===================== 4-phase 128x128 GEMM (proj path only) =====================
// Proven on proj since R5. NOT for QKV (R9: 70.5us vs gemm256's 51.3).
template <int I0, int J0>
__device__ __forceinline__ void mfma8(f32x4 (&acc)[4][4], bf16x8 (&af)[2][2],
                                      bf16x8 (&bfr)[4][2]) {
  __builtin_amdgcn_s_setprio(1);
#pragma unroll
  for (int kk = 0; kk < 2; ++kk)
#pragma unroll
    for (int i = 0; i < 2; ++i)
#pragma unroll
      for (int j = 0; j < 2; ++j)
        acc[I0 + i][J0 + j] = __builtin_amdgcn_mfma_f32_16x16x32_bf16(
            bfr[J0 + j][kk], af[i][kk], acc[I0 + i][J0 + j], 0, 0, 0);
  __builtin_amdgcn_s_setprio(0);
}

__global__ __launch_bounds__(256, 2) void gemm128(const __bf16* __restrict__ A,
                                                  const __bf16* __restrict__ Bt,
                                                  const float* __restrict__ bias,
                                                  void* __restrict__ C,
                                                  int M, int N, int K, int store_bf16) {
  __shared__ __attribute__((aligned(1024))) __bf16 As[2][128 * 64];
  __shared__ __attribute__((aligned(1024))) __bf16 Bs[2][128 * 64];

  const int t = threadIdx.x;
  const int lane = t & 63, wave = t >> 6;
  const int quad = lane >> 4, l15 = lane & 15;
  const int wm = wave >> 1, wn = wave & 1;

  // XCD-bijective block swizzle (grid 320 = 8*40)
  const int mb = M >> 7;
  const int cpx = gridDim.x >> 3;
  const int wg = (blockIdx.x & 7) * cpx + (blockIdx.x >> 3);
  const int bm = (wg % mb) * 128, bn = (wg / mb) * 128;

  const __bf16* Ab = A + (size_t)bm * K;
  const __bf16* Bb = Bt + (size_t)bn * K;

  auto stage = [&](const __bf16* g, __bf16* l, int row0, int kt) {
    GLD_LDS16(g + (size_t)(row0 + (lane >> 3)) * K + kt * 64 +
                  (((lane & 7) ^ ((lane >> 3) & 7)) << 3),
              l + row0 * 64);
  };
  auto lda2 = [&](bf16x8 (&dst)[2][2], const __bf16* Al, int I0) {
#pragma unroll
    for (int i = 0; i < 2; ++i)
#pragma unroll
      for (int kk = 0; kk < 2; ++kk) {
        int row = wm * 64 + (I0 + i) * 16 + l15;
        int c = (kk * 64 + quad * 16) ^ ((l15 & 7) << 4);
        dst[i][kk] = *(const bf16x8*)&Al[row * 64 + (c >> 1)];
      }
  };
  auto ldb2 = [&](bf16x8 (&dst)[2][2], const __bf16* Bl, int J0) {
#pragma unroll
    for (int j = 0; j < 2; ++j)
#pragma unroll
      for (int kk = 0; kk < 2; ++kk) {
        int row = wn * 64 + (J0 + j) * 16 + l15;
        int c = (kk * 64 + quad * 16) ^ ((l15 & 7) << 4);
        dst[j][kk] = *(const bf16x8*)&Bl[row * 64 + (c >> 1)];
      }
  };

  const int aw = wave * 8;   // wave's 8-row slice within a 32-row quarter
  const int niter = K >> 6;

  // Region map (rows): Ae/Be = {0..31, 64..95}; Ao/Bo = {32..63, 96..127}.
  stage(Ab, As[0], aw, 0);        stage(Ab, As[0], 64 + aw, 0);   // t0.Ae
  stage(Bb, Bs[0], aw, 0);        stage(Bb, Bs[0], 64 + aw, 0);   // t0.Be
  stage(Ab, As[0], 32 + aw, 0);   stage(Ab, As[0], 96 + aw, 0);   // t0.Ao
  stage(Bb, Bs[0], 32 + aw, 0);   stage(Bb, Bs[0], 96 + aw, 0);   // t0.Bo
  stage(Ab, As[1], aw, 1);        stage(Ab, As[1], 64 + aw, 1);   // t1.Ae
  stage(Bb, Bs[1], aw, 1);        stage(Bb, Bs[1], 64 + aw, 1);   // t1.Be
  WAIT_VMCNT(4);
  BARRIER;

  f32x4 acc[4][4] = {};
  bf16x8 af[2][2], bfr[4][2];

  for (int it = 0; it < niter; ++it) {
    const int cur = it & 1;
    const __bf16* Ac = As[cur];
    const __bf16* Bc = Bs[cur];
    __bf16* An = As[cur ^ 1];
    __bf16* Bn = Bs[cur ^ 1];
    const bool p1 = it + 1 < niter, p2 = it + 2 < niter;

    // ph1: read A(i0-1)+B(j0-1) [Ae/Be]; stage (t+1).Ao
    lda2(af, Ac, 0);
    ldb2(reinterpret_cast<bf16x8(&)[2][2]>(bfr[0]), Bc, 0);
    if (p1) { stage(Ab, An, 32 + aw, it + 1); stage(Ab, An, 96 + aw, it + 1); }
    BARRIER;
    mfma8<0, 0>(acc, af, bfr);
    BARRIER;

    // ph2: read B(j2-3) [Bo]; stage (t+1).Bo
    ldb2(reinterpret_cast<bf16x8(&)[2][2]>(bfr[2]), Bc, 2);
    if (p1) { stage(Bb, Bn, 32 + aw, it + 1); stage(Bb, Bn, 96 + aw, it + 1); }
    BARRIER;
    mfma8<0, 2>(acc, af, bfr);
    BARRIER;

    // ph3: read A(i2-3) [Ao]; stage (t+2).Ae into cur (dead since ph1)
    lda2(af, Ac, 2);
    if (p2) { stage(Ab, (__bf16*)Ac, aw, it + 2); stage(Ab, (__bf16*)Ac, 64 + aw, it + 2); }
    BARRIER;
    mfma8<2, 0>(acc, af, bfr);
    BARRIER;

    // ph4: pure-reg MFMA; stage (t+2).Be into cur (dead since ph1); counted vmcnt
    if (p2) { stage(Bb, (__bf16*)Bc, aw, it + 2); stage(Bb, (__bf16*)Bc, 64 + aw, it + 2); }
    BARRIER;
    mfma8<2, 2>(acc, af, bfr);
    if (p2) { WAIT_VMCNT(4); }   // drains t+1.Ao/Bo; leaves t+2.Ae/Be in flight
    else    { WAIT_VMCNT(0); }   // tail: full drain
    BARRIER;
  }

  float4 bv4[4];
#pragma unroll
  for (int j = 0; j < 4; ++j)
    bv4[j] = *(const float4*)&bias[bn + wn * 64 + j * 16 + quad * 4];
#pragma unroll
  for (int i = 0; i < 4; ++i) {
    size_t row = (size_t)(bm + wm * 64 + i * 16 + l15);
#pragma unroll
    for (int j = 0; j < 4; ++j) {
      int col = bn + wn * 64 + j * 16 + quad * 4;
      const float* bp = (const float*)&bv4[j];
      if (store_bf16) {
        bf16x4 ov;
#pragma unroll
        for (int r = 0; r < 4; ++r) ov[r] = (__bf16)(acc[i][j][r] + bp[r]);
        *(bf16x4*)&((__bf16*)C)[row * N + col] = ov;
      } else {
        float4 fv;
        fv.x = acc[i][j][0] + bp[0];
        fv.y = acc[i][j][1] + bp[1];
        fv.z = acc[i][j][2] + bp[2];
        fv.w = acc[i][j][3] + bp[3];
        *(float4*)&((float*)C)[row * N + col] = fv;
      }
    }
  }
}

// --- RoPE q,k + pack (vectorized b128 loads/stores; on-device trig):
//   qp, kp: (H, S, 96), d 80..95 zero; q pre-scaled by log2e/sqrt(80)
//   vt: per-head, per-32-key tiles [80 d][40 pos], KEY-PERMUTED
//   (permutation == x32 MFMA operand k->key map; PV consumes vv directly)
__global__ __launch_bounds__(256) void rope_pack(const __bf16* __restrict__ qkv,
                                                 const float* __restrict__ freqs,
                                                 __bf16* __restrict__ qp,
                                                 __bf16* __restrict__ kp,
                                                 __bf16* __restrict__ vt) {
  const float QSCALE = 0.11180339887498949f * 1.44269504088896340f;
  int h = blockIdx.y;
  int s0 = blockIdx.x * 64;
  int t = threadIdx.x;
  int sp = t >> 2, l4 = t & 3;
  int s = s0 + sp;
  const __bf16* row = qkv + (size_t)s * 3840 + h * 80;
  __bf16* qo = qp + (size_t)(h * SLEN + s) * HDP;
  __bf16* ko = kp + (size_t)(h * SLEN + s) * HDP;

  __shared__ float vtile[64][81];

  for (int c = l4; c < 10; c += 4) {
    int base = (c < 5) ? c * 8 : (c - 5) * 8;
    bf16x8 xa = *(const bf16x8*)(row + base);
    bf16x8 xb = *(const bf16x8*)(row + base + 40);
    bf16x8 ya = *(const bf16x8*)(row + 1280 + base);
    bf16x8 yb = *(const bf16x8*)(row + 1280 + base + 40);
    float4 f0 = *(const float4*)(freqs + s * 40 + base);
    float4 f1 = *(const float4*)(freqs + s * 40 + base + 4);
    float fr[8] = {f0.x, f0.y, f0.z, f0.w, f1.x, f1.y, f1.z, f1.w};
    bf16x8 qv, kv;
#pragma unroll
    for (int e = 0; e < 8; ++e) {
      float cs = __builtin_cosf(fr[e]), sn = __builtin_sinf(fr[e]);
      float x1 = (float)xa[e], x2 = (float)xb[e];
      float y1 = (float)ya[e], y2 = (float)yb[e];
      float qvv, kvv;
      if (c < 5) { qvv = x1 * cs - x2 * sn; kvv = y1 * cs - y2 * sn; }
      else       { qvv = x1 * sn + x2 * cs; kvv = y1 * sn + y2 * cs; }
      qv[e] = (__bf16)(qvv * QSCALE);
      kv[e] = (__bf16)kvv;
    }
    *(bf16x8*)(qo + c * 8) = qv;
    *(bf16x8*)(ko + c * 8) = kv;
  }
  {
    bf16x8 z = {};
    if (l4 == 0) *(bf16x8*)(qo + 80) = z;
    if (l4 == 1) *(bf16x8*)(qo + 88) = z;
    if (l4 == 2) *(bf16x8*)(ko + 80) = z;
    if (l4 == 3) *(bf16x8*)(ko + 88) = z;
  }

  for (int c = l4; c < 10; c += 4) {
    bf16x8 v = *(const bf16x8*)(row + 2560 + c * 8);
#pragma unroll
    for (int e = 0; e < 8; ++e)
      vtile[sp][c * 8 + e] = (float)v[e];
  }
  __syncthreads();

  for (int idx = t; idx < 640; idx += 256) {
    int c2 = idx >= 320;
    int rem = idx - (c2 ? 320 : 0);
    int d = rem >> 2, kc = rem & 3;
    __bf16* tb = vt + (size_t)(h * (SLEN / 32) + (s0 >> 5) + c2) * VTILE_ELEMS;
    bf16x8 ov;
#pragma unroll
    for (int r = 0; r < 4; ++r) {
      ov[r]     = (__bf16)vtile[c2 * 32 + kc * 4 + r][d];
      ov[r + 4] = (__bf16)vtile[c2 * 32 + 16 + kc * 4 + r][d];
    }
    *(bf16x8*)(tb + d * 40 + kc * 8) = ov;
  }
}

// ----------------- flash attention: 32 q-rows/wave, b128 V reads -----------------
// PV x32 MFMA (R3); T5 setprio (R4); XCD-locality remap (R8, kept: -1.6us).
__global__ __launch_bounds__(256) void flash_attn(const __bf16* __restrict__ qp,
                                                  const __bf16* __restrict__ kp,
                                                  const __bf16* __restrict__ vt,
                                                  const int* __restrict__ cu, int nseg,
                                                  __bf16* __restrict__ out) {
  const float MEXP = 16.0f;
  int bid = blockIdx.x;
  int p = bid & 63;            // (head, quarter) pair
  int qs8 = bid >> 6;          // q sub-tile 0..7
  int h = p >> 2;
  int q0 = (p & 3) * (SLEN / 4) + qs8 * 128;
  int seg = 0;
  for (int i = 1; i < nseg; ++i)
    if (cu[i] <= q0) seg = i;
  int kstart = cu[seg], kend = cu[seg + 1];

  int t = threadIdx.x;
  int lane = t & 63, wave = t >> 6;
  int quad = lane >> 4, l15 = lane & 15;

  __shared__ __attribute__((aligned(16))) __bf16 Ks[2][64 * HDP];       // 2x12288 B
  __shared__ __attribute__((aligned(16))) __bf16 Vs[2][2 * VTILE_LDS];  // 2x14336 B

  bf16x8 qf[2][3];
#pragma unroll
  for (int qs = 0; qs < 2; ++qs) {
    const __bf16* qptr = qp + (size_t)(h * SLEN + q0 + wave * 32 + qs * 16 + l15) * HDP + quad * 8;
    qf[qs][0] = *(const bf16x8*)(qptr);
    qf[qs][1] = *(const bf16x8*)(qptr + 32);
    qf[qs][2] = *(const bf16x8*)(qptr + 64);
  }

  f32x4 o[2][5] = {};
  float l_p[2] = {0.f, 0.f};

  const __bf16* gK = kp + (size_t)(h * SLEN + kstart) * HDP + lane * 8;
  const __bf16* gV = vt + (size_t)(h * (SLEN / 32) + (kstart >> 5)) * VTILE_ELEMS + lane * 8;

  const int niter = (kend - kstart) >> 6;

  auto stage = [&](int kn, int buf) {
    const __bf16* ksrc = gK + (size_t)kn * (64 * HDP);
    const __bf16* vsrc = gV + (size_t)kn * (2 * VTILE_ELEMS);
#pragma unroll
    for (int i0 = 0; i0 < 7; ++i0) {
      int i = wave * 7 + i0;
      int ii = i < 26 ? i : 25;   // dummies re-issue slot 25 (idempotent)
      if (ii < 12)
        GLD_LDS16(ksrc + ii * 512, &Ks[buf][ii * 512]);
      else if (ii < 19)
        GLD_LDS16(vsrc + (ii - 12) * 512, &Vs[buf][(ii - 12) * 512]);
      else
        GLD_LDS16(vsrc + VTILE_ELEMS + (ii - 19) * 512, &Vs[buf][VTILE_LDS + (ii - 19) * 512]);
    }
  };

  stage(0, 0);

  for (int it = 0; it < niter; ++it) {
    const int cur = it & 1, nxt = cur ^ 1;
    const int kn = (it + 1 < niter) ? it + 1 : niter - 1;
    stage(kn, nxt);
    asm volatile("" ::: "memory");
    WAIT_VMCNT(7);
    __builtin_amdgcn_s_barrier();
    asm volatile("" ::: "memory");

    f32x4 sc[2][4];
    __builtin_amdgcn_s_setprio(1);
#pragma unroll
    for (int nt = 0; nt < 4; ++nt) {
      sc[0][nt] = f32x4{-MEXP, -MEXP, -MEXP, -MEXP};
      sc[1][nt] = sc[0][nt];
#pragma unroll
      for (int c = 0; c < 3; ++c) {
        bf16x8 kf = *(const bf16x8*)&Ks[cur][(nt * 16 + l15) * HDP + quad * 8 + c * 32];
        sc[0][nt] = __builtin_amdgcn_mfma_f32_16x16x32_bf16(kf, qf[0][c], sc[0][nt], 0, 0, 0);
        sc[1][nt] = __builtin_amdgcn_mfma_f32_16x16x32_bf16(kf, qf[1][c], sc[1][nt], 0, 0, 0);
      }
    }
    __builtin_amdgcn_s_setprio(0);

    bf16x4 pf[2][4];
#pragma unroll
    for (int qs = 0; qs < 2; ++qs)
#pragma unroll
      for (int nt = 0; nt < 4; ++nt)
#pragma unroll
        for (int r = 0; r < 4; ++r) {
          float pexp = __builtin_amdgcn_exp2f(sc[qs][nt][r]);
          l_p[qs] += pexp;
          pf[qs][nt][r] = (__bf16)pexp;
        }

    __builtin_amdgcn_s_setprio(1);
#pragma unroll
    for (int g = 0; g < 2; ++g) {
      bf16x8 pc[2];
#pragma unroll
      for (int qs = 0; qs < 2; ++qs)
        pc[qs] = __builtin_shufflevector(pf[qs][g * 2], pf[qs][g * 2 + 1],
                                         0, 1, 2, 3, 4, 5, 6, 7);
#pragma unroll
      for (int dt = 0; dt < 5; ++dt) {
        bf16x8 vv = *(const bf16x8*)&Vs[cur][g * VTILE_LDS + (dt * 16 + l15) * 40 + quad * 8];
#pragma unroll
        for (int qs = 0; qs < 2; ++qs)
          o[qs][dt] = __builtin_amdgcn_mfma_f32_16x16x32_bf16(vv, pc[qs], o[qs][dt], 0, 0, 0);
      }
    }
    __builtin_amdgcn_s_setprio(0);

    asm volatile("" ::: "memory");
    __builtin_amdgcn_s_barrier();
    asm volatile("" ::: "memory");
  }

#pragma unroll
  for (int qs = 0; qs < 2; ++qs) {
    float l = l_p[qs];
    l += __shfl_xor(l, 16);
    l += __shfl_xor(l, 32);
    float rinv = 1.0f / l;
    int qrow = q0 + wave * 32 + qs * 16 + l15;
#pragma unroll
    for (int dt = 0; dt < 5; ++dt) {
      bf16x4 ov;
#pragma unroll
      for (int r = 0; r < 4; ++r)
        ov[r] = (__bf16)(o[qs][dt][r] * rinv);
      *(bf16x4*)&out[(size_t)qrow * DMODEL + h * 80 + dt * 16 + quad * 4] = ov;
    }
  }
}

extern "C" void kernel_launch(void* const* d_in, const int* in_sizes, int n_in,
                              void* d_out, int out_size, void* d_ws, size_t ws_size,
                              hipStream_t stream) {
  const float* hidden = (const float*)d_in[0];
  const int* cu       = (const int*)d_in[1];
  const float* freqs  = (const float*)d_in[2];
  const float* w_qkv  = (const float*)d_in[3];
  const float* b_qkv  = (const float*)d_in[4];
  const float* w_proj = (const float*)d_in[5];
  const float* b_proj = (const float*)d_in[6];
  float* out = (float*)d_out;

  char* ws = (char*)d_ws;
  size_t off = 0;
  auto alloc = [&](size_t bytes) {
    char* p = ws + off;
    off += (bytes + 255) & ~(size_t)255;
    return p;
  };
  __bf16* hid_b  = (__bf16*)alloc((size_t)SLEN * DMODEL * 2);
  __bf16* wqkvT  = (__bf16*)alloc((size_t)3840 * 1280 * 2);
  __bf16* wprojT = (__bf16*)alloc((size_t)1280 * 1280 * 2);
  __bf16* qkvb   = (__bf16*)alloc((size_t)SLEN * 3840 * 2);
  __bf16* qp     = (__bf16*)alloc((size_t)NHEADS * SLEN * HDP * 2);
  __bf16* kp     = (__bf16*)alloc((size_t)NHEADS * SLEN * HDP * 2 + 1024);
  __bf16* vt     = (__bf16*)alloc((size_t)NHEADS * (SLEN / 32) * VTILE_ELEMS * 2 + 1024);
  __bf16* attn   = hid_b;  // alias: hid_b dead after qkv GEMM

  prep<<<11520, 256, 0, stream>>>(hidden, hid_b, w_qkv, wqkvT, w_proj, wprojT);
  gemm256<<<dim3((SLEN / 256) * (3840 / 256)), 512, 0, stream>>>(hid_b, wqkvT, b_qkv, qkvb,
                                                                 SLEN, 3840, 1280);
  rope_pack<<<dim3(SLEN / 64, NHEADS), 256, 0, stream>>>(qkvb, freqs, qp, kp, vt);
  int nseg = in_sizes[1] - 1;
  flash_attn<<<dim3((SLEN / 128) * NHEADS), 256, 0, stream>>>(qp, kp, vt, cu, nseg, attn);
  gemm128<<<dim3((SLEN / 128) * (DMODEL / 128)), 256, 0, stream>>>(attn, wprojT, b_proj, out,
                                                                   SLEN, DMODEL, 1280, 0);
}